// Round 6
// baseline (221.789 us; speedup 1.0000x reference)
//
#include <hip/hip_runtime.h>
#include <hip/hip_bf16.h>

// Problem dims (fixed): B=4, N=256, D=512, L=3
#define BB 4
#define NN 256
#define DD 512

using short8   = __attribute__((ext_vector_type(8))) short;
using f32x4    = __attribute__((ext_vector_type(4))) float;
using uint32x4 = __attribute__((ext_vector_type(4))) unsigned int;

__device__ __forceinline__ unsigned short f2bf(float f) {
    unsigned int u = __float_as_uint(f);
    unsigned int r = (u + 0x7fffu + ((u >> 16) & 1u)) >> 16;
    return (unsigned short)r;
}

// packed f32->bf16 (RNE), 2 elems/instr
__device__ __forceinline__ unsigned cvtpk(float lo, float hi) {
    unsigned r;
    asm("v_cvt_pk_bf16_f32 %0, %1, %2" : "=v"(r) : "v"(lo), "v"(hi));
    return r;
}

// Stage a ROWSx64 bf16 tile from row-major global (stride elems) into LDS,
// XOR-swizzled: LDS slot s of row r holds global 16B-slot (s ^ (r&7)).
// global_load_lds width 16, linear LDS dest, pre-swizzled global source.
template <int ROWS, int NW>
__device__ __forceinline__ void stage_rows(const unsigned short* src, int stride,
                                           short* dst, int tid) {
    int wave = tid >> 6, lane = tid & 63;
#pragma unroll
    for (int c = 0; c < ROWS / (8 * NW); ++c) {
        int rbase = (c * NW + wave) * 8;
        int row   = rbase + (lane >> 3);
        int slot  = (lane & 7) ^ (row & 7);
        const unsigned short* g = src + (size_t)row * stride + slot * 8;
        __builtin_amdgcn_global_load_lds(
            (const __attribute__((address_space(1))) void*)g,
            (__attribute__((address_space(3))) void*)(dst + rbase * 64),
            16, 0, 0);
    }
}

// Partial stage for 512-row tile, 8 waves: c in [C0,C1), each c = 64 rows.
template <int C0, int C1>
__device__ __forceinline__ void stage_part(const unsigned short* src, int stride,
                                           short* dst, int tid) {
    int wave = tid >> 6, lane = tid & 63;
#pragma unroll
    for (int c = C0; c < C1; ++c) {
        int rbase = (c * 8 + wave) * 8;
        int row   = rbase + (lane >> 3);
        int slot  = (lane & 7) ^ (row & 7);
        const unsigned short* g = src + (size_t)row * stride + slot * 8;
        __builtin_amdgcn_global_load_lds(
            (const __attribute__((address_space(1))) void*)g,
            (__attribute__((address_space(3))) void*)(dst + rbase * 64),
            16, 0, 0);
    }
}

// Read an MFMA A/B fragment (16 rows x 32 k) from a swizzled [ROWS][64] bf16 tile.
__device__ __forceinline__ short8 read_frag(const short* T, int rowBase, int k2) {
    int lane = threadIdx.x & 63;
    int row  = rowBase + (lane & 15);
    int slot = ((k2 * 4) + (lane >> 4)) ^ (row & 7);
    return *(const short8*)(T + row * 64 + slot * 8);
}

// ---------------- prep: fp32 -> bf16 weight conversion + h0 init ----------------
__global__ void prep_kernel(const float* __restrict__ x,
                            const float* __restrict__ gw, const float* __restrict__ tw,
                            const float* __restrict__ w0, const float* __restrict__ w1,
                            float* __restrict__ h0_f32, unsigned short* __restrict__ h0_bf,
                            unsigned short* __restrict__ wg_bf, unsigned short* __restrict__ wt_bf,
                            unsigned short* __restrict__ w0c_bf, unsigned short* __restrict__ w1_bf) {
    const int S_X = BB * NN * DD;
    const int S_W = 3 * DD * DD;
    const int S_W0 = 2 * DD * DD;
    int total = S_X + S_W + S_W + S_W0 + DD * DD;
    for (int idx = blockIdx.x * blockDim.x + threadIdx.x; idx < total;
         idx += gridDim.x * blockDim.x) {
        int t = idx;
        if (t < S_X) { float v = x[t]; h0_f32[t] = v; h0_bf[t] = f2bf(v); continue; }
        t -= S_X;
        if (t < S_W) { wg_bf[t] = f2bf(gw[t]); continue; }
        t -= S_W;
        if (t < S_W) { wt_bf[t] = f2bf(tw[t]); continue; }
        t -= S_W;
        if (t < S_W0) {
            int e = t >> 9, d = t & 511;
            float v = (e < DD) ? w0[e * (2 * DD) + d] : w0[(e - DD) * (2 * DD) + DD + d];
            w0c_bf[t] = f2bf(v); continue;
        }
        t -= S_W0;
        w1_bf[t] = f2bf(w1[t]);
    }
}

// ---------------- highway layer (64x64 tiles, 4 waves, 128 blocks) ----------------
__global__ __launch_bounds__(256) void highway_kernel(
        const float* __restrict__ h_in, const unsigned short* __restrict__ hbf_in,
        const unsigned short* __restrict__ wg_bf, const unsigned short* __restrict__ wt_bf,
        const float* __restrict__ gb, const float* __restrict__ tb,
        float* __restrict__ h_out, unsigned short* __restrict__ hbf_out) {
    __shared__ short ht[64 * 64];
    __shared__ short wgt[64 * 64];
    __shared__ short wtt[64 * 64];
    int tid = threadIdx.x, lane = tid & 63, wave = tid >> 6;
    int mt = blockIdx.x >> 3, et = blockIdx.x & 7;
    int m0 = mt * 64, e0 = et * 64;
    int wm = wave >> 1, we = wave & 1;
    f32x4 gacc[2][2] = {}, tacc[2][2] = {};
    for (int ks = 0; ks < 8; ++ks) {
        int d0 = ks * 64;
        __syncthreads();
        stage_rows<64, 4>(hbf_in + (size_t)m0 * DD + d0, DD, ht, tid);
        stage_rows<64, 4>(wg_bf + (size_t)e0 * DD + d0, DD, wgt, tid);
        stage_rows<64, 4>(wt_bf + (size_t)e0 * DD + d0, DD, wtt, tid);
        __syncthreads();
#pragma unroll
        for (int k2 = 0; k2 < 2; ++k2) {
            short8 af[2], bg[2], bt[2];
#pragma unroll
            for (int f = 0; f < 2; ++f) af[f] = read_frag(ht, wm * 32 + f * 16, k2);
#pragma unroll
            for (int f = 0; f < 2; ++f) bg[f] = read_frag(wgt, we * 32 + f * 16, k2);
#pragma unroll
            for (int f = 0; f < 2; ++f) bt[f] = read_frag(wtt, we * 32 + f * 16, k2);
#pragma unroll
            for (int fm = 0; fm < 2; ++fm)
#pragma unroll
                for (int fn = 0; fn < 2; ++fn) {
                    gacc[fm][fn] = __builtin_amdgcn_mfma_f32_16x16x32_bf16(af[fm], bg[fn], gacc[fm][fn], 0, 0, 0);
                    tacc[fm][fn] = __builtin_amdgcn_mfma_f32_16x16x32_bf16(af[fm], bt[fn], tacc[fm][fn], 0, 0, 0);
                }
        }
    }
#pragma unroll
    for (int fm = 0; fm < 2; ++fm)
#pragma unroll
        for (int fn = 0; fn < 2; ++fn) {
            int e = e0 + we * 32 + fn * 16 + (lane & 15);
            float gbe = gb[e], tbe = tb[e];
#pragma unroll
            for (int r = 0; r < 4; ++r) {
                int m = m0 + wm * 32 + fm * 16 + (lane >> 4) * 4 + r;
                float g = 1.f / (1.f + __expf(-(gacc[fm][fn][r] + gbe)));
                float tv = tacc[fm][fn][r] + tbe; tv = tv > 0.f ? tv : 0.f;
                float ho = h_in[(size_t)m * DD + e];
                float hn = g * tv + (1.f - g) * ho;
                h_out[(size_t)m * DD + e] = hn;
                hbf_out[(size_t)m * DD + e] = f2bf(hn);
            }
        }
}

// ---------------- a/b projection (64x128 tiles, 4 waves, 128 blocks) ------------
__global__ __launch_bounds__(256) void ab_kernel(
        const unsigned short* __restrict__ hbf, const unsigned short* __restrict__ w0c_bf,
        const float* __restrict__ lw0_b,
        float* __restrict__ a_out, float* __restrict__ b_out) {
    __shared__ short ht[64 * 64];
    __shared__ short wt_[128 * 64];
    int tid = threadIdx.x, lane = tid & 63, wave = tid >> 6;
    int mt = blockIdx.x >> 3, et = blockIdx.x & 7;
    int m0 = mt * 64, e0 = et * 128;
    int wm = wave >> 1, we = wave & 1;
    f32x4 acc[2][4] = {};
    for (int ks = 0; ks < 8; ++ks) {
        __syncthreads();
        stage_rows<64, 4>(hbf + (size_t)m0 * DD + ks * 64, DD, ht, tid);
        stage_rows<128, 4>(w0c_bf + (size_t)e0 * DD + ks * 64, DD, wt_, tid);
        __syncthreads();
#pragma unroll
        for (int k2 = 0; k2 < 2; ++k2) {
            short8 af[2], bf_[4];
#pragma unroll
            for (int f = 0; f < 2; ++f) af[f] = read_frag(ht, wm * 32 + f * 16, k2);
#pragma unroll
            for (int f = 0; f < 4; ++f) bf_[f] = read_frag(wt_, we * 64 + f * 16, k2);
#pragma unroll
            for (int fm = 0; fm < 2; ++fm)
#pragma unroll
                for (int fn = 0; fn < 4; ++fn)
                    acc[fm][fn] = __builtin_amdgcn_mfma_f32_16x16x32_bf16(af[fm], bf_[fn], acc[fm][fn], 0, 0, 0);
        }
    }
#pragma unroll
    for (int fm = 0; fm < 2; ++fm)
#pragma unroll
        for (int fn = 0; fn < 4; ++fn) {
            int e = e0 + we * 64 + fn * 16 + (lane & 15);
#pragma unroll
            for (int r = 0; r < 4; ++r) {
                int m = m0 + wm * 32 + fm * 16 + (lane >> 4) * 4 + r;
                float v = acc[fm][fn][r];
                if (e < DD) a_out[(size_t)m * DD + e] = v + lw0_b[e];
                else        b_out[(size_t)m * DD + (e - DD)] = v;
            }
        }
}

// ---------------- fused pairwise kernel (v6: 4-phase, explicit drains) --------
// Same 4-phase interleave as v5, but W1-stage completion is guaranteed by
// EXPLICIT s_waitcnt vmcnt(0): (a) end of prologue (v5 bug: implicit wait was
// only vmcnt(8) because a/b loads were issued before the stage -> first step
// read a partially-staged / stale ws[0]); (b) phase 3 before the step
// boundary (v5 relied on compiler not reordering a/b vs stage issues).
// Issue-to-drain distance ~2 phases, so both waits are normally satisfied.

#define Z_LOADS(K)                                                            \
    {                                                                         \
        const int dl_ = (K) * 64 + s * 8;                                     \
        alo = *(const f32x4*)(arow + dl_);                                    \
        ahi = *(const f32x4*)(arow + dl_ + 4);                                \
        const float* b0_ = brow + (size_t)rr * DD + dl_;                      \
        const float* b1_ = brow + (size_t)(64 + rr) * DD + dl_;               \
        b0lo = *(const f32x4*)b0_; b0hi = *(const f32x4*)(b0_ + 4);           \
        b1lo = *(const f32x4*)b1_; b1hi = *(const f32x4*)(b1_ + 4);           \
    }

#define Z_MATH()                                                              \
    {                                                                         \
        zw0[0] = cvtpk(fmaxf(alo[0] + b0lo[0], 0.f), fmaxf(alo[1] + b0lo[1], 0.f)); \
        zw0[1] = cvtpk(fmaxf(alo[2] + b0lo[2], 0.f), fmaxf(alo[3] + b0lo[3], 0.f)); \
        zw0[2] = cvtpk(fmaxf(ahi[0] + b0hi[0], 0.f), fmaxf(ahi[1] + b0hi[1], 0.f)); \
        zw0[3] = cvtpk(fmaxf(ahi[2] + b0hi[2], 0.f), fmaxf(ahi[3] + b0hi[3], 0.f)); \
        zw1[0] = cvtpk(fmaxf(alo[0] + b1lo[0], 0.f), fmaxf(alo[1] + b1lo[1], 0.f)); \
        zw1[1] = cvtpk(fmaxf(alo[2] + b1lo[2], 0.f), fmaxf(alo[3] + b1lo[3], 0.f)); \
        zw1[2] = cvtpk(fmaxf(ahi[0] + b1hi[0], 0.f), fmaxf(ahi[1] + b1hi[1], 0.f)); \
        zw1[3] = cvtpk(fmaxf(ahi[2] + b1hi[2], 0.f), fmaxf(ahi[3] + b1hi[3], 0.f)); \
    }

#define Z_WRITE(BUF)                                                          \
    {                                                                         \
        *(uint32x4*)((BUF) + rr * 64 + ((s ^ (rr & 7)) * 8)) = zw0;           \
        const int r1_ = 64 + rr;                                              \
        *(uint32x4*)((BUF) + r1_ * 64 + ((s ^ (r1_ & 7)) * 8)) = zw1;         \
    }

#define LGKM0_FENCE                                                           \
    asm volatile("s_waitcnt lgkmcnt(0)" ::: "memory");                        \
    __builtin_amdgcn_sched_barrier(0);

#define VM0_FENCE                                                             \
    asm volatile("s_waitcnt vmcnt(0)" ::: "memory");                          \
    __builtin_amdgcn_sched_barrier(0);

#define MFMA_Q(ABASE, BFR)                                                    \
    __builtin_amdgcn_s_setprio(1);                                            \
    _Pragma("unroll")                                                         \
    for (int fm = 0; fm < 4; ++fm)                                            \
        _Pragma("unroll")                                                     \
        for (int fn = 0; fn < 4; ++fn)                                        \
            acc[(ABASE) + fm][fn] = __builtin_amdgcn_mfma_f32_16x16x32_bf16(  \
                af[fm], (BFR)[fn], acc[(ABASE) + fm][fn], 0, 0, 0);           \
    __builtin_amdgcn_s_setprio(0);

__global__ __launch_bounds__(512, 2) void pair_kernel(
        const float* __restrict__ a_f32, const float* __restrict__ b_f32,
        const unsigned short* __restrict__ w1_bf,
        const float* __restrict__ lw1_b, const float* __restrict__ lwo_w,
        const float* __restrict__ lwo_b, float* __restrict__ out) {
    __shared__ short ws[2][512 * 64];   // 128KB W1 double buffer
    __shared__ short zs[2][128 * 64];   // 32KB z double buffer; s_red alias after loop
    int tid = threadIdx.x, lane = tid & 63, wave = tid >> 6;
    int bid = blockIdx.x;
    // bijective XCD swizzle: each XCD's blocks cover a contiguous i-range
    int swz = (bid & 7) * 256 + (bid >> 3);
    int bb = swz >> 9, i = (swz >> 1) & 255, j0 = (swz & 1) * 128;
    const float* arow = a_f32 + (size_t)(bb * NN + i) * DD;
    const float* brow = b_f32 + (size_t)(bb * NN + j0) * DD;
    int s = tid & 7, rr = tid >> 3;     // z producer coords (rr: 0..63)
    int we = wave;                       // e-slice owner: e in [we*64, we*64+64)

    f32x4 acc[8][4] = {};
    uint32x4 zw0, zw1;
    f32x4 alo, ahi, b0lo, b0hi, b1lo, b1hi;

    // ---- prologue: z[0] + W1[0] ----
    Z_LOADS(0)
    stage_part<0, 8>(w1_bf, DD, ws[0], tid);
    Z_MATH()
    Z_WRITE(zs[0])
    asm volatile("s_waitcnt lgkmcnt(0)" ::: "memory");
    VM0_FENCE                            // ws[0] DMA fully landed (v5 bug fix)
    __builtin_amdgcn_s_barrier();        // zs[0] + ws[0] valid for all waves

#pragma unroll
    for (int k = 0; k < 8; ++k) {
        const short* zc = zs[k & 1];
        const short* wc = ws[k & 1];
        short8 af[4], bfr0[4], bfr1[4];

        // ---------- phase 0: k2=0, fh=0; stage W1(k+1) rows 0-255 ----------
#pragma unroll
        for (int f = 0; f < 4; ++f) bfr0[f] = read_frag(wc, we * 64 + f * 16, 0);
#pragma unroll
        for (int f = 0; f < 4; ++f) af[f] = read_frag(zc, f * 16, 0);
        if (k < 7) stage_part<0, 4>(w1_bf + (size_t)(k + 1) * 64, DD,
                                    ws[(k + 1) & 1], tid);
        __builtin_amdgcn_s_barrier();
        LGKM0_FENCE
        MFMA_Q(0, bfr0)
        __builtin_amdgcn_s_barrier();

        // ---------- phase 1: k2=0, fh=1; stage rows 256-511, then a/b loads ----
#pragma unroll
        for (int f = 0; f < 4; ++f) af[f] = read_frag(zc, 64 + f * 16, 0);
        if (k < 7) {
            stage_part<4, 8>(w1_bf + (size_t)(k + 1) * 64, DD, ws[(k + 1) & 1], tid);
            Z_LOADS(k + 1)
        }
        __builtin_amdgcn_s_barrier();
        LGKM0_FENCE
        MFMA_Q(4, bfr0)
        __builtin_amdgcn_s_barrier();

        // ---------- phase 2: k2=1, fh=0; z-math+z-write in MFMA shadow ----------
#pragma unroll
        for (int f = 0; f < 4; ++f) bfr1[f] = read_frag(wc, we * 64 + f * 16, 1);
#pragma unroll
        for (int f = 0; f < 4; ++f) af[f] = read_frag(zc, f * 16, 1);
        __builtin_amdgcn_s_barrier();
        LGKM0_FENCE
        MFMA_Q(0, bfr1)
        if (k < 7) {
            Z_MATH()                     // implicit wait for a/b regs
            Z_WRITE(zs[(k + 1) & 1])
        }
        __builtin_amdgcn_s_barrier();

        // ---------- phase 3: k2=1, fh=1 ----------
#pragma unroll
        for (int f = 0; f < 4; ++f) af[f] = read_frag(zc, 64 + f * 16, 1);
        __builtin_amdgcn_s_barrier();
        LGKM0_FENCE                      // also drains this wave's z-writes
        MFMA_Q(4, bfr1)
        VM0_FENCE                        // ws[(k+1)&1] DMA fully landed (explicit)
        __builtin_amdgcn_s_barrier();    // step boundary: zs/ws[(k+1)&1] valid
    }

    // ---- epilogue: relu(acc+b1)*wo, reduce over all e ----
    __syncthreads();                     // all zs reads done -> alias as s_red
    float* s_red = (float*)zs;           // 8 waves x 128 j partials
#pragma unroll
    for (int fm = 0; fm < 8; ++fm) {
        float red[4] = {0.f, 0.f, 0.f, 0.f};
#pragma unroll
        for (int fn = 0; fn < 4; ++fn) {
            int e = we * 64 + fn * 16 + (lane & 15);
            float b1e = lw1_b[e], woe = lwo_w[e];
#pragma unroll
            for (int r = 0; r < 4; ++r) {
                float v = acc[fm][fn][r] + b1e;
                red[r] += (v > 0.f) ? v * woe : 0.f;
            }
        }
#pragma unroll
        for (int mask = 1; mask < 16; mask <<= 1)
#pragma unroll
            for (int r = 0; r < 4; ++r) red[r] += __shfl_xor(red[r], mask, 64);
        if ((lane & 15) == 0) {
#pragma unroll
            for (int r = 0; r < 4; ++r)
                s_red[we * 128 + fm * 16 + (lane >> 4) * 4 + r] = red[r];
        }
    }
    __syncthreads();
    if (tid < 128) {
        float v = lwo_b[0];
#pragma unroll
        for (int w8 = 0; w8 < 8; ++w8) v += s_red[w8 * 128 + tid];
        out[((size_t)(bb * NN + i)) * NN + j0 + tid] = 1.f / (1.f + __expf(-v));
    }
}

extern "C" void kernel_launch(void* const* d_in, const int* in_sizes, int n_in,
                              void* d_out, int out_size, void* d_ws, size_t ws_size,
                              hipStream_t stream) {
    const float* x    = (const float*)d_in[0];
    const float* gw   = (const float*)d_in[1];
    const float* gb   = (const float*)d_in[2];
    const float* tw   = (const float*)d_in[3];
    const float* tb   = (const float*)d_in[4];
    const float* w0   = (const float*)d_in[5];
    const float* w0b  = (const float*)d_in[6];
    const float* w1   = (const float*)d_in[7];
    const float* w1b_ = (const float*)d_in[8];
    const float* wo   = (const float*)d_in[9];
    const float* wob  = (const float*)d_in[10];
    float* out = (float*)d_out;

    char* w = (char*)d_ws;
    float* hA  = (float*)w;            w += (size_t)BB * NN * DD * 4;
    float* hB  = (float*)w;            w += (size_t)BB * NN * DD * 4;
    unsigned short* hbA = (unsigned short*)w; w += (size_t)BB * NN * DD * 2;
    unsigned short* hbB = (unsigned short*)w; w += (size_t)BB * NN * DD * 2;
    float* a_f = (float*)w;            w += (size_t)BB * NN * DD * 4;
    float* b_f = (float*)w;            w += (size_t)BB * NN * DD * 4;
    unsigned short* wg_bf  = (unsigned short*)w; w += (size_t)3 * DD * DD * 2;
    unsigned short* wt_bf  = (unsigned short*)w; w += (size_t)3 * DD * DD * 2;
    unsigned short* w0c_bf = (unsigned short*)w; w += (size_t)2 * DD * DD * 2;
    unsigned short* w1_bf  = (unsigned short*)w; w += (size_t)DD * DD * 2;

    prep_kernel<<<1024, 256, 0, stream>>>(x, gw, tw, w0, w1, hA, hbA, wg_bf, wt_bf, w0c_bf, w1_bf);

    highway_kernel<<<128, 256, 0, stream>>>(hA, hbA, wg_bf + 0 * DD * DD, wt_bf + 0 * DD * DD,
                                            gb + 0 * DD, tb + 0 * DD, hB, hbB);
    highway_kernel<<<128, 256, 0, stream>>>(hB, hbB, wg_bf + 1 * DD * DD, wt_bf + 1 * DD * DD,
                                            gb + 1 * DD, tb + 1 * DD, hA, hbA);
    highway_kernel<<<128, 256, 0, stream>>>(hA, hbA, wg_bf + 2 * DD * DD, wt_bf + 2 * DD * DD,
                                            gb + 2 * DD, tb + 2 * DD, hB, hbB);

    ab_kernel<<<128, 256, 0, stream>>>(hbB, w0c_bf, w0b, a_f, b_f);

    pair_kernel<<<2048, 512, 0, stream>>>(a_f, b_f, w1_bf, w1b_, wo, wob, out);
}